// Round 1
// baseline (289.285 us; speedup 1.0000x reference)
//
#include <hip/hip_runtime.h>
#include <math.h>

// Problem is fixed-shape: N=8192 rows, D=4096 cols, fp32 in, fp32 scalar out.
#define N_ROWS 8192
#define D_COLS 4096
#define MARGIN 5.0f

// ---------------------------------------------------------------------------
// init: zero the double accumulator in workspace (ws is poisoned 0xAA per call)
__global__ void init_kernel(double* __restrict__ sum) { *sum = 0.0; }

// ---------------------------------------------------------------------------
// dist: one block per row. d[i] = sqrt(sum_j (rx-x)^2) + 0.001
// dp[i] = (t==1) ? d : -inf   (anchor-positive rows)
// dn[i] = (t==0) ? d : +inf   (negative rows)
// The +-inf encoding makes max(0, dp_i + M - dn_j) exactly 0 for masked pairs.
__global__ __launch_bounds__(256) void dist_kernel(
    const float* __restrict__ rx, const float* __restrict__ x,
    const int* __restrict__ tgt, float* __restrict__ dp, float* __restrict__ dn) {
  const int row = blockIdx.x;
  const float4* a = reinterpret_cast<const float4*>(rx) + (size_t)row * (D_COLS / 4);
  const float4* b = reinterpret_cast<const float4*>(x)  + (size_t)row * (D_COLS / 4);
  float s = 0.f;
#pragma unroll
  for (int k = 0; k < D_COLS / 4 / 256; ++k) {       // 4 float4 per thread
    float4 va = a[threadIdx.x + k * 256];
    float4 vb = b[threadIdx.x + k * 256];
    float d0 = va.x - vb.x, d1 = va.y - vb.y, d2 = va.z - vb.z, d3 = va.w - vb.w;
    s = fmaf(d0, d0, s); s = fmaf(d1, d1, s);
    s = fmaf(d2, d2, s); s = fmaf(d3, d3, s);
  }
#pragma unroll
  for (int off = 32; off; off >>= 1) s += __shfl_down(s, off, 64);  // wave=64
  __shared__ float ws[4];
  const int lane = threadIdx.x & 63, wid = threadIdx.x >> 6;
  if (lane == 0) ws[wid] = s;
  __syncthreads();
  if (threadIdx.x == 0) {
    float tot = ws[0] + ws[1] + ws[2] + ws[3];
    float dd = sqrtf(tot) + 0.001f;
    int t = tgt[row];
    dp[row] = (t == 1) ? dd : -INFINITY;
    dn[row] = (t == 0) ? dd : INFINITY;
  }
}

// ---------------------------------------------------------------------------
// pairs: each thread holds 32 dn values in registers; blocks stride over i.
// Non-positive rows (dp==-inf) are skipped wave-uniformly; the hinge is
// self-masking via +-inf anyway (never produces NaN: only -inf - (+inf)).
__global__ __launch_bounds__(256) void pair_kernel(
    const float* __restrict__ dp, const float* __restrict__ dn,
    double* __restrict__ sum) {
  float r[N_ROWS / 256];
#pragma unroll
  for (int k = 0; k < N_ROWS / 256; ++k) r[k] = dn[threadIdx.x + k * 256];
  float acc = 0.f;
  for (int i = blockIdx.x; i < N_ROWS; i += gridDim.x) {
    float dpi = dp[i];                 // uniform across block
    if (dpi == -INFINITY) continue;    // wave-uniform branch
    float dpi5 = dpi + MARGIN;
#pragma unroll
    for (int k = 0; k < N_ROWS / 256; ++k) acc += fmaxf(dpi5 - r[k], 0.f);
  }
#pragma unroll
  for (int off = 32; off; off >>= 1) acc += __shfl_down(acc, off, 64);
  __shared__ float ws[4];
  const int lane = threadIdx.x & 63, wid = threadIdx.x >> 6;
  if (lane == 0) ws[wid] = acc;
  __syncthreads();
  if (threadIdx.x == 0)
    atomicAdd(sum, (double)(ws[0] + ws[1] + ws[2] + ws[3]));
}

// ---------------------------------------------------------------------------
// finalize: count positives (targets in {0,1} so n_neg = N - n_pos), divide.
__global__ __launch_bounds__(256) void final_kernel(
    const int* __restrict__ tgt, const double* __restrict__ sum,
    float* __restrict__ out) {
  int c = 0;
#pragma unroll
  for (int k = 0; k < N_ROWS / 256; ++k) c += (tgt[threadIdx.x + k * 256] == 1);
#pragma unroll
  for (int off = 32; off; off >>= 1) c += __shfl_down(c, off, 64);
  __shared__ int ws[4];
  const int lane = threadIdx.x & 63, wid = threadIdx.x >> 6;
  if (lane == 0) ws[wid] = c;
  __syncthreads();
  if (threadIdx.x == 0) {
    long long np = ws[0] + ws[1] + ws[2] + ws[3];
    long long cnt = np * (long long)(N_ROWS - np);
    out[0] = (float)(*sum / (double)cnt);
  }
}

// ---------------------------------------------------------------------------
extern "C" void kernel_launch(void* const* d_in, const int* in_sizes, int n_in,
                              void* d_out, int out_size, void* d_ws, size_t ws_size,
                              hipStream_t stream) {
  const float* rx  = (const float*)d_in[0];
  const float* x   = (const float*)d_in[1];
  const int*   tgt = (const int*)d_in[2];
  float* out = (float*)d_out;

  // workspace layout: dp[8192] f32 | dn[8192] f32 | sum f64 (8-aligned)
  float*  dp  = (float*)d_ws;
  float*  dn  = dp + N_ROWS;
  double* sum = (double*)(dn + N_ROWS);

  init_kernel<<<1, 1, 0, stream>>>(sum);
  dist_kernel<<<N_ROWS, 256, 0, stream>>>(rx, x, tgt, dp, dn);
  pair_kernel<<<1024, 256, 0, stream>>>(dp, dn, sum);
  final_kernel<<<1, 256, 0, stream>>>(tgt, sum, out);
}